// Round 8
// baseline (6162.039 us; speedup 1.0000x reference)
//
#include <hip/hip_runtime.h>
#include <math.h>

// dims
#define SDIM 2048
#define LDIM 16
#define ECD 64
#define HCD 128
#define EWD 300
#define HWD 512
#define DWD 556
#define FCD 512
#define OUTD 20

typedef unsigned int uint32;

// ws layout (float offsets)
static constexpr int OFF_CWIHT = 0;         // [2][64][512]   = 65536
static constexpr int OFF_CWHHT = 65536;     // [2][128][512]  = 131072
static constexpr int OFF_CENC  = 196608;    // [2048][256]    = 524288
static constexpr int OFF_WC    = 720896;    // [2048][556]    = 1138688
static constexpr int OFF_H     = 1859584;   // [2][2049][512] = 2098176 (uint32 bit patterns)
static constexpr int OFF_HFIN  = 3957760;   // [1024]
// total ~15.8 MB of ws

#define SENT 0xFFFFFFFFu   // -NaN bit pattern; h = sigmoid*tanh in (-1,1) never produces it
#define HSLOT 1049088      // 2049*512

__device__ __forceinline__ float sigmoidf_(float x) {
    return 1.0f / (1.0f + __expf(-x));
}
__device__ __forceinline__ float tanhf_(float x) {
    x = fminf(10.0f, fmaxf(-10.0f, x));
    float e2 = __expf(2.0f * x);
    return (e2 - 1.0f) / (e2 + 1.0f);
}

// ---------------- K0: transpose char weights + sentinel-fill h slots ----------------
__global__ void k0_prep(const float* __restrict__ cWih_f, const float* __restrict__ cWhh_f,
                        const float* __restrict__ cWih_b, const float* __restrict__ cWhh_b,
                        float* __restrict__ ws) {
    const int nt = gridDim.x * blockDim.x;
    const int t0 = blockIdx.x * blockDim.x + threadIdx.x;
    float* cWihT = ws + OFF_CWIHT;
    float* cWhhT = ws + OFF_CWHHT;
    uint32* hT = (uint32*)(ws + OFF_H);
    for (int i = t0; i < 2 * 512 * 64; i += nt) {
        int d = i / (512 * 64), rem = i % (512 * 64);
        int r = rem / 64, k = rem % 64;
        const float* src = d ? cWih_b : cWih_f;
        cWihT[(d * 64 + k) * 512 + r] = src[r * 64 + k];
    }
    for (int i = t0; i < 2 * 512 * 128; i += nt) {
        int d = i / (512 * 128), rem = i % (512 * 128);
        int r = rem / 128, k = rem % 128;
        const float* src = d ? cWhh_b : cWhh_f;
        cWhhT[(d * 128 + k) * 512 + r] = src[r * 128 + k];
    }
    // h slots: slot 0 = zeros (h_{-1}), slots 1..2048 = sentinel
    for (int i = t0; i < 2 * HSLOT; i += nt) {
        int rel = i % HSLOT;
        hT[i] = (rel < 512) ? 0u : SENT;
    }
}

// ---------------- K1: char BiLSTM (batch 2048, T=16) ----------------
__global__ __launch_bounds__(256) void k1_charlstm(
        const int* __restrict__ sc, const float* __restrict__ cemb,
        float* __restrict__ ws,
        const float* __restrict__ cbih_f, const float* __restrict__ cbhh_f,
        const float* __restrict__ cbih_b, const float* __restrict__ cbhh_b) {
    const int tid = threadIdx.x;
    const int dir = blockIdx.x >> 8;
    const int w0 = (blockIdx.x & 255) * 8;
    const float* WihT = ws + OFF_CWIHT + dir * 64 * 512;   // [64][512]
    const float* WhhT = ws + OFF_CWHHT + dir * 128 * 512;  // [128][512]
    float* char_enc = ws + OFF_CENC;
    const float* bih = dir ? cbih_b : cbih_f;
    const float* bhh = dir ? cbhh_b : cbhh_f;

    __shared__ __align__(16) float x_lds[8][64];
    __shared__ __align__(16) float h_lds[8][128];
    __shared__ float fo_lds[2][8][128];

    const int r0 = tid, r1 = tid + 256;
    const float bz0 = bih[r0] + bhh[r0];
    const float bz1 = bih[r1] + bhh[r1];

    for (int i = tid; i < 8 * 128; i += 256) ((float*)h_lds)[i] = 0.0f;
    float c[8];
#pragma unroll
    for (int w = 0; w < 8; w++) c[w] = 0.0f;
    __syncthreads();

    for (int t = 0; t < 16; t++) {
        const int tx = dir ? (15 - t) : t;
        {   // gather x: 8 words x 64 dims
            int w = tid >> 6, e = tid & 63;
            int i0 = sc[(w0 + w) * 16 + tx];
            x_lds[w][e] = cemb[i0 * 64 + e];
            int i1 = sc[(w0 + w + 4) * 16 + tx];
            x_lds[w + 4][e] = cemb[i1 * 64 + e];
        }
        __syncthreads();

        float a0[8], a1[8];
#pragma unroll
        for (int w = 0; w < 8; w++) { a0[w] = bz0; a1[w] = bz1; }

        // Wih part (K=64)
        for (int k = 0; k < 64; k += 4) {
            float w00 = WihT[(k + 0) * 512 + r0], w01 = WihT[(k + 1) * 512 + r0];
            float w02 = WihT[(k + 2) * 512 + r0], w03 = WihT[(k + 3) * 512 + r0];
            float w10 = WihT[(k + 0) * 512 + r1], w11 = WihT[(k + 1) * 512 + r1];
            float w12 = WihT[(k + 2) * 512 + r1], w13 = WihT[(k + 3) * 512 + r1];
#pragma unroll
            for (int w = 0; w < 8; w++) {
                float4 xq = *(const float4*)&x_lds[w][k];
                a0[w] += w00 * xq.x + w01 * xq.y + w02 * xq.z + w03 * xq.w;
                a1[w] += w10 * xq.x + w11 * xq.y + w12 * xq.z + w13 * xq.w;
            }
        }
        // Whh part (K=128)
        for (int k = 0; k < 128; k += 4) {
            float w00 = WhhT[(k + 0) * 512 + r0], w01 = WhhT[(k + 1) * 512 + r0];
            float w02 = WhhT[(k + 2) * 512 + r0], w03 = WhhT[(k + 3) * 512 + r0];
            float w10 = WhhT[(k + 0) * 512 + r1], w11 = WhhT[(k + 1) * 512 + r1];
            float w12 = WhhT[(k + 2) * 512 + r1], w13 = WhhT[(k + 3) * 512 + r1];
#pragma unroll
            for (int w = 0; w < 8; w++) {
                float4 hq = *(const float4*)&h_lds[w][k];
                a0[w] += w00 * hq.x + w01 * hq.y + w02 * hq.z + w03 * hq.w;
                a1[w] += w10 * hq.x + w11 * hq.y + w12 * hq.z + w13 * hq.w;
            }
        }
        if (tid >= 128) {
            int e = tid - 128;
#pragma unroll
            for (int w = 0; w < 8; w++) { fo_lds[0][w][e] = a0[w]; fo_lds[1][w][e] = a1[w]; }
        }
        __syncthreads();
        if (tid < 128) {
            int e = tid;
#pragma unroll
            for (int w = 0; w < 8; w++) {
                float zi = a0[w], zg = a1[w];
                float zf = fo_lds[0][w][e], zo = fo_lds[1][w][e];
                float cn = sigmoidf_(zf) * c[w] + sigmoidf_(zi) * tanhf_(zg);
                c[w] = cn;
                h_lds[w][e] = sigmoidf_(zo) * tanhf_(cn);
            }
        }
        __syncthreads();
    }
    if (tid < 128) {
        int e = tid;
        for (int w = 0; w < 8; w++)
            char_enc[(w0 + w) * 256 + dir * 128 + e] = h_lds[w][e];
    }
}

// ---------------- K2: build wc = [word_emb | char_enc] ----------------
__global__ void k2_wc(const int* __restrict__ sw, const float* __restrict__ wemb,
                      float* __restrict__ ws) {
    const int t = blockIdx.x;
    const int tid = threadIdx.x;
    const float* char_enc = ws + OFF_CENC;
    float* wc = ws + OFF_WC;
    const int widx = sw[t];
    for (int k = tid; k < 300; k += 256) wc[t * 556 + k] = wemb[widx * 300 + k];
    for (int k = tid; k < 256; k += 256) wc[t * 556 + 300 + k] = char_enc[t * 256 + k];
}

// ---------------- K4: word BiLSTM, persistent, dedicated-poller + wide polls -------
// 128 blocks = 2 dirs x 64 slices; 5 waves (320 thr). Waves 0-3 compute (wave w owns
// h-elems E0+2w, E0+2w+1; lane=r*8+s, gate q=r>>1, parity e=r&1, s splits K 8 ways).
// Wave 4 is a dedicated poller: polls h_t with 2 coherent dwordx4 loads/lane
// (sc0 sc1 -> serviced at the coherent point; 4x fewer fabric requests than scalar),
// falls back to known-correct scalar agent atomics after 4 rounds, stages to LDS,
// lgkmcnt drain, flag bump, and immediately polls the next step. Compute waves spin
// on the LDS flag, FMA, wave-local cell, publish, then prefetch ip for t+1 in the
// spin shadow. NO barriers in the loop (dataflow bounds wave skew: poller cannot see
// h_{t+2} complete before this block's computes published t+1, which is after they
// finished reading hbuf[t]).
__global__ __launch_bounds__(320, 1) void k4_wordlstm(
        const float* __restrict__ wWih_f, const float* __restrict__ wWhh_f,
        const float* __restrict__ wbih_f, const float* __restrict__ wbhh_f,
        const float* __restrict__ wWih_b, const float* __restrict__ wWhh_b,
        const float* __restrict__ wbih_b, const float* __restrict__ wbhh_b,
        float* __restrict__ ws) {
    const int tid = threadIdx.x;
    const int w = tid >> 6;               // wave 0..4
    const int lane = tid & 63;
    const int dir = blockIdx.x >> 6;
    const int slice = blockIdx.x & 63;
    const int E0 = slice * 8;

    const float* wc = ws + OFF_WC;
    uint32* hT = (uint32*)(ws + OFF_H) + (size_t)dir * HSLOT;
    float* hfin = ws + OFF_HFIN;

    __shared__ __align__(16) uint32 hbuf[2][512];  // staged h double buffer
    __shared__ int flag[2];                        // per-parity arrival flags

    if (tid < 2) flag[tid] = 0;
    __syncthreads();   // one-time init barrier (outside the loop)

    if (w == 4) {
        // ================= POLLER WAVE =================
        const int b0 = 4 * lane;          // words [b0, b0+4)
        const int b1 = 256 + 4 * lane;    // words [b1, b1+4)
        for (int t = 0; t < 2048; t++) {
            const int par = t & 1;
            uint32* hs = hT + (size_t)t * 512;
            uint4 a, b;
            bool ok = false;
            // wide coherent spin (few rounds)
            for (int round = 0; round < 4; round++) {
                asm volatile(
                    "global_load_dwordx4 %0, %2, off sc0 sc1\n\t"
                    "global_load_dwordx4 %1, %3, off sc0 sc1\n\t"
                    "s_waitcnt vmcnt(0)"
                    : "=&v"(a), "=&v"(b)
                    : "v"(&hs[b0]), "v"(&hs[b1])
                    : "memory");
                uint32 bad = (a.x == SENT) | (a.y == SENT) | (a.z == SENT) | (a.w == SENT)
                           | (b.x == SENT) | (b.y == SENT) | (b.z == SENT) | (b.w == SENT);
                if (!__any(bad)) { ok = true; break; }
            }
            if (!ok) {
                // scalar agent-atomic fallback (known-correct coherence path)
                while (true) {
                    uint32 v[8];
#pragma unroll
                    for (int m = 0; m < 4; m++)
                        v[m] = __hip_atomic_load(&hs[b0 + m], __ATOMIC_RELAXED, __HIP_MEMORY_SCOPE_AGENT);
#pragma unroll
                    for (int m = 0; m < 4; m++)
                        v[4 + m] = __hip_atomic_load(&hs[b1 + m], __ATOMIC_RELAXED, __HIP_MEMORY_SCOPE_AGENT);
                    uint32 bad = 0;
#pragma unroll
                    for (int m = 0; m < 8; m++) bad |= (v[m] == SENT) ? 1u : 0u;
                    if (!__any(bad)) {
                        a.x = v[0]; a.y = v[1]; a.z = v[2]; a.w = v[3];
                        b.x = v[4]; b.y = v[5]; b.z = v[6]; b.w = v[7];
                        break;
                    }
                }
            }
            // stage to LDS + flag bump
            *(uint4*)&hbuf[par][b0] = a;
            *(uint4*)&hbuf[par][b1] = b;
            asm volatile("s_waitcnt lgkmcnt(0)" ::: "memory");
            if (lane == 0) *(volatile int*)&flag[par] = t + 1;
        }
        return;
    }

    // ================= COMPUTE WAVES =================
    const int r = lane >> 3, s = lane & 7;
    const int q = r >> 1, e = r & 1;
    const int elem = E0 + 2 * w + e;
    const int grow = q * 512 + elem;      // this lane's gate row

    const float* Wih = dir ? wWih_b : wWih_f;
    const float* Whh = dir ? wWhh_b : wWhh_f;
    const float* bih = dir ? wbih_b : wbih_f;
    const float* bhh = dir ? wbhh_b : wbhh_f;

    const float bz = bih[grow] + bhh[grow];
    const float bzs = (s == 0) ? bz : 0.0f;   // add bias exactly once per row

    // Whh row chunks -> registers (chunk idx = s+8j, j=0..15)
    float4 wr[16];
#pragma unroll
    for (int j = 0; j < 16; j++)
        wr[j] = *(const float4*)&Whh[grow * 512 + (s + 8 * j) * 4];
    // Wih row chunks -> registers (139 float4 chunks; cc = s+8*cj)
    float4 wih[18];
#pragma unroll
    for (int cj = 0; cj < 18; cj++) {
        int cc = s + 8 * cj;
        if (cc < 139) wih[cj] = *(const float4*)&Wih[grow * 556 + cc * 4];
        else { wih[cj].x = wih[cj].y = wih[cj].z = wih[cj].w = 0.0f; }
    }

    float cstate = 0.0f;
    const int eh = lane >> 5;              // which of the wave's 2 elems this half updates

    // input projection for t=0 (per-lane partial from global wc; L2-hit loads)
    float acc_ih = bzs;
    {
        const float* wcrow = wc + (size_t)(dir ? 2047 : 0) * 556;
#pragma unroll
        for (int cj = 0; cj < 18; cj++) {
            int cc = s + 8 * cj;
            if (cc < 139) {
                float4 b = *(const float4*)&wcrow[cc * 4];
                acc_ih += wih[cj].x * b.x + wih[cj].y * b.y + wih[cj].z * b.z + wih[cj].w * b.w;
            }
        }
    }

    for (int t = 0; t < 2048; t++) {
        const int par = t & 1;
        // --- wait for staged h_t (cheap LDS spin) ---
        while (*(volatile int*)&flag[par] < t + 1) { }
        asm volatile("" ::: "memory");
        // --- recurrent FMA from LDS (b128 reads, conflict-free) ---
        float acc = acc_ih;
        {
            const float* hb = (const float*)hbuf[par];
#pragma unroll
            for (int j = 0; j < 16; j++) {
                float4 hq = *(const float4*)&hb[(s + 8 * j) * 4];
                acc += wr[j].x * hq.x + wr[j].y * hq.y + wr[j].z * hq.z + wr[j].w * hq.w;
            }
        }
        // --- butterfly reduce over K-split (s bits) ---
        acc += __shfl_xor(acc, 1);
        acc += __shfl_xor(acc, 2);
        acc += __shfl_xor(acc, 4);
        // --- gather 4 gates for this half's elem; wave-parallel cell update ---
        float zi = __shfl(acc, 8 * eh);          // row eh     (gate i)
        float zf = __shfl(acc, 16 + 8 * eh);     // row 2+eh   (gate f)
        float zg = __shfl(acc, 32 + 8 * eh);     // row 4+eh   (gate g)
        float zo = __shfl(acc, 48 + 8 * eh);     // row 6+eh   (gate o)
        float cn = sigmoidf_(zf) * cstate + sigmoidf_(zi) * tanhf_(zg);
        cstate = cn;
        float hv = sigmoidf_(zo) * tanhf_(cn);
        // --- publish h_{t+1} immediately (lanes 0 and 32 of each wave) ---
        if ((lane & 31) == 0) {
            int eidx = E0 + 2 * w + eh;
            __hip_atomic_store(&hT[(size_t)(t + 1) * 512 + eidx], __float_as_uint(hv),
                               __ATOMIC_RELAXED, __HIP_MEMORY_SCOPE_AGENT);
            if (t == 2047) hfin[dir * 512 + eidx] = hv;
        }
        // --- input projection for t+1 (hidden in next spin window) ---
        if (t < 2047) {
            acc_ih = bzs;
            const float* wcrow = wc + (size_t)(dir ? (2046 - t) : (t + 1)) * 556;
#pragma unroll
            for (int cj = 0; cj < 18; cj++) {
                int cc = s + 8 * cj;
                if (cc < 139) {
                    float4 b = *(const float4*)&wcrow[cc * 4];
                    acc_ih += wih[cj].x * b.x + wih[cj].y * b.y + wih[cj].z * b.z + wih[cj].w * b.w;
                }
            }
        }
    }
}

// ---------------- K5: classifier head + softmax ----------------
__global__ __launch_bounds__(256) void k5_head(
        const float* __restrict__ ws,
        const float* __restrict__ fc1_w, const float* __restrict__ fc1_b,
        const float* __restrict__ fc2_w, const float* __restrict__ fc2_b,
        float* __restrict__ out) {
    __shared__ float hl[1024];
    __shared__ float z1[512];
    __shared__ float z2[20];
    const int tid = threadIdx.x;
    const float* hfin = ws + OFF_HFIN;
    for (int i = tid; i < 1024; i += 256) hl[i] = hfin[i];
    __syncthreads();
    for (int o = tid; o < 512; o += 256) {
        float a = fc1_b[o];
        const float* wrow = fc1_w + o * 1024;
        for (int k = 0; k < 1024; k++) a += wrow[k] * hl[k];
        z1[o] = fmaxf(a, 0.0f);
    }
    __syncthreads();
    if (tid < 20) {
        float a = fc2_b[tid];
        const float* wrow = fc2_w + tid * 512;
        for (int k = 0; k < 512; k++) a += wrow[k] * z1[k];
        z2[tid] = a;
    }
    __syncthreads();
    if (tid == 0) {
        float m = -1e30f;
        for (int i = 0; i < 20; i++) m = fmaxf(m, z2[i]);
        float sum = 0.0f, ex[20];
        for (int i = 0; i < 20; i++) { ex[i] = __expf(z2[i] - m); sum += ex[i]; }
        for (int i = 0; i < 20; i++) out[i] = ex[i] / sum;
    }
}

extern "C" void kernel_launch(void* const* d_in, const int* in_sizes, int n_in,
                              void* d_out, int out_size, void* d_ws, size_t ws_size,
                              hipStream_t stream) {
    const int*   sc     = (const int*)d_in[0];
    const int*   sw     = (const int*)d_in[1];
    const float* cemb   = (const float*)d_in[2];
    const float* cWih_f = (const float*)d_in[3];
    const float* cWhh_f = (const float*)d_in[4];
    const float* cbih_f = (const float*)d_in[5];
    const float* cbhh_f = (const float*)d_in[6];
    const float* cWih_b = (const float*)d_in[7];
    const float* cWhh_b = (const float*)d_in[8];
    const float* cbih_b = (const float*)d_in[9];
    const float* cbhh_b = (const float*)d_in[10];
    const float* wemb   = (const float*)d_in[11];
    const float* wWih_f = (const float*)d_in[12];
    const float* wWhh_f = (const float*)d_in[13];
    const float* wbih_f = (const float*)d_in[14];
    const float* wbhh_f = (const float*)d_in[15];
    const float* wWih_b = (const float*)d_in[16];
    const float* wWhh_b = (const float*)d_in[17];
    const float* wbih_b = (const float*)d_in[18];
    const float* wbhh_b = (const float*)d_in[19];
    const float* fc1_w  = (const float*)d_in[20];
    const float* fc1_b  = (const float*)d_in[21];
    const float* fc2_w  = (const float*)d_in[22];
    const float* fc2_b  = (const float*)d_in[23];
    float* ws = (float*)d_ws;
    float* out = (float*)d_out;

    k0_prep<<<256, 256, 0, stream>>>(cWih_f, cWhh_f, cWih_b, cWhh_b, ws);
    k1_charlstm<<<512, 256, 0, stream>>>(sc, cemb, ws, cbih_f, cbhh_f, cbih_b, cbhh_b);
    k2_wc<<<2048, 256, 0, stream>>>(sw, wemb, ws);
    k4_wordlstm<<<128, 320, 0, stream>>>(wWih_f, wWhh_f, wbih_f, wbhh_f,
                                         wWih_b, wWhh_b, wbih_b, wbhh_b, ws);
    k5_head<<<1, 256, 0, stream>>>(ws, fc1_w, fc1_b, fc2_w, fc2_b, out);
}

// Round 9
// 5522.799 us; speedup vs baseline: 1.1157x; 1.1157x over previous
//
#include <hip/hip_runtime.h>
#include <math.h>

// dims
#define SDIM 2048
#define LDIM 16
#define ECD 64
#define HCD 128
#define EWD 300
#define HWD 512
#define DWD 556
#define FCD 512
#define OUTD 20

typedef unsigned int uint32;

// ws layout (float offsets)
static constexpr int OFF_CWIHT = 0;         // [2][64][512]   = 65536
static constexpr int OFF_CWHHT = 65536;     // [2][128][512]  = 131072
static constexpr int OFF_CENC  = 196608;    // [2048][256]    = 524288
static constexpr int OFF_WC    = 720896;    // [2048][556]    = 1138688
static constexpr int OFF_H     = 1859584;   // [2][2049][512] = 2098176 (uint32 bit patterns)
static constexpr int OFF_HFIN  = 3957760;   // [1024]
// total ~15.8 MB of ws

#define SENT 0xFFFFFFFFu   // -NaN bit pattern; h = sigmoid*tanh in (-1,1) never produces it
#define HSLOT 1049088      // 2049*512

__device__ __forceinline__ float sigmoidf_(float x) {
    return 1.0f / (1.0f + __expf(-x));
}
__device__ __forceinline__ float tanhf_(float x) {
    x = fminf(10.0f, fmaxf(-10.0f, x));
    float e2 = __expf(2.0f * x);
    return (e2 - 1.0f) / (e2 + 1.0f);
}

// ---------------- K0: transpose char weights + sentinel-fill h slots ----------------
__global__ void k0_prep(const float* __restrict__ cWih_f, const float* __restrict__ cWhh_f,
                        const float* __restrict__ cWih_b, const float* __restrict__ cWhh_b,
                        float* __restrict__ ws) {
    const int nt = gridDim.x * blockDim.x;
    const int t0 = blockIdx.x * blockDim.x + threadIdx.x;
    float* cWihT = ws + OFF_CWIHT;
    float* cWhhT = ws + OFF_CWHHT;
    uint32* hT = (uint32*)(ws + OFF_H);
    for (int i = t0; i < 2 * 512 * 64; i += nt) {
        int d = i / (512 * 64), rem = i % (512 * 64);
        int r = rem / 64, k = rem % 64;
        const float* src = d ? cWih_b : cWih_f;
        cWihT[(d * 64 + k) * 512 + r] = src[r * 64 + k];
    }
    for (int i = t0; i < 2 * 512 * 128; i += nt) {
        int d = i / (512 * 128), rem = i % (512 * 128);
        int r = rem / 128, k = rem % 128;
        const float* src = d ? cWhh_b : cWhh_f;
        cWhhT[(d * 128 + k) * 512 + r] = src[r * 128 + k];
    }
    // h slots: slot 0 = zeros (h_{-1}), slots 1..2048 = sentinel
    for (int i = t0; i < 2 * HSLOT; i += nt) {
        int rel = i % HSLOT;
        hT[i] = (rel < 512) ? 0u : SENT;
    }
}

// ---------------- K1: char BiLSTM (batch 2048, T=16) ----------------
__global__ __launch_bounds__(256) void k1_charlstm(
        const int* __restrict__ sc, const float* __restrict__ cemb,
        float* __restrict__ ws,
        const float* __restrict__ cbih_f, const float* __restrict__ cbhh_f,
        const float* __restrict__ cbih_b, const float* __restrict__ cbhh_b) {
    const int tid = threadIdx.x;
    const int dir = blockIdx.x >> 8;
    const int w0 = (blockIdx.x & 255) * 8;
    const float* WihT = ws + OFF_CWIHT + dir * 64 * 512;   // [64][512]
    const float* WhhT = ws + OFF_CWHHT + dir * 128 * 512;  // [128][512]
    float* char_enc = ws + OFF_CENC;
    const float* bih = dir ? cbih_b : cbih_f;
    const float* bhh = dir ? cbhh_b : cbhh_f;

    __shared__ __align__(16) float x_lds[8][64];
    __shared__ __align__(16) float h_lds[8][128];
    __shared__ float fo_lds[2][8][128];

    const int r0 = tid, r1 = tid + 256;
    const float bz0 = bih[r0] + bhh[r0];
    const float bz1 = bih[r1] + bhh[r1];

    for (int i = tid; i < 8 * 128; i += 256) ((float*)h_lds)[i] = 0.0f;
    float c[8];
#pragma unroll
    for (int w = 0; w < 8; w++) c[w] = 0.0f;
    __syncthreads();

    for (int t = 0; t < 16; t++) {
        const int tx = dir ? (15 - t) : t;
        {   // gather x: 8 words x 64 dims
            int w = tid >> 6, e = tid & 63;
            int i0 = sc[(w0 + w) * 16 + tx];
            x_lds[w][e] = cemb[i0 * 64 + e];
            int i1 = sc[(w0 + w + 4) * 16 + tx];
            x_lds[w + 4][e] = cemb[i1 * 64 + e];
        }
        __syncthreads();

        float a0[8], a1[8];
#pragma unroll
        for (int w = 0; w < 8; w++) { a0[w] = bz0; a1[w] = bz1; }

        // Wih part (K=64)
        for (int k = 0; k < 64; k += 4) {
            float w00 = WihT[(k + 0) * 512 + r0], w01 = WihT[(k + 1) * 512 + r0];
            float w02 = WihT[(k + 2) * 512 + r0], w03 = WihT[(k + 3) * 512 + r0];
            float w10 = WihT[(k + 0) * 512 + r1], w11 = WihT[(k + 1) * 512 + r1];
            float w12 = WihT[(k + 2) * 512 + r1], w13 = WihT[(k + 3) * 512 + r1];
#pragma unroll
            for (int w = 0; w < 8; w++) {
                float4 xq = *(const float4*)&x_lds[w][k];
                a0[w] += w00 * xq.x + w01 * xq.y + w02 * xq.z + w03 * xq.w;
                a1[w] += w10 * xq.x + w11 * xq.y + w12 * xq.z + w13 * xq.w;
            }
        }
        // Whh part (K=128)
        for (int k = 0; k < 128; k += 4) {
            float w00 = WhhT[(k + 0) * 512 + r0], w01 = WhhT[(k + 1) * 512 + r0];
            float w02 = WhhT[(k + 2) * 512 + r0], w03 = WhhT[(k + 3) * 512 + r0];
            float w10 = WhhT[(k + 0) * 512 + r1], w11 = WhhT[(k + 1) * 512 + r1];
            float w12 = WhhT[(k + 2) * 512 + r1], w13 = WhhT[(k + 3) * 512 + r1];
#pragma unroll
            for (int w = 0; w < 8; w++) {
                float4 hq = *(const float4*)&h_lds[w][k];
                a0[w] += w00 * hq.x + w01 * hq.y + w02 * hq.z + w03 * hq.w;
                a1[w] += w10 * hq.x + w11 * hq.y + w12 * hq.z + w13 * hq.w;
            }
        }
        if (tid >= 128) {
            int e = tid - 128;
#pragma unroll
            for (int w = 0; w < 8; w++) { fo_lds[0][w][e] = a0[w]; fo_lds[1][w][e] = a1[w]; }
        }
        __syncthreads();
        if (tid < 128) {
            int e = tid;
#pragma unroll
            for (int w = 0; w < 8; w++) {
                float zi = a0[w], zg = a1[w];
                float zf = fo_lds[0][w][e], zo = fo_lds[1][w][e];
                float cn = sigmoidf_(zf) * c[w] + sigmoidf_(zi) * tanhf_(zg);
                c[w] = cn;
                h_lds[w][e] = sigmoidf_(zo) * tanhf_(cn);
            }
        }
        __syncthreads();
    }
    if (tid < 128) {
        int e = tid;
        for (int w = 0; w < 8; w++)
            char_enc[(w0 + w) * 256 + dir * 128 + e] = h_lds[w][e];
    }
}

// ---------------- K2: build wc = [word_emb | char_enc] ----------------
__global__ void k2_wc(const int* __restrict__ sw, const float* __restrict__ wemb,
                      float* __restrict__ ws) {
    const int t = blockIdx.x;
    const int tid = threadIdx.x;
    const float* char_enc = ws + OFF_CENC;
    float* wc = ws + OFF_WC;
    const int widx = sw[t];
    for (int k = tid; k < 300; k += 256) wc[t * 556 + k] = wemb[widx * 300 + k];
    for (int k = tid; k < 256; k += 256) wc[t * 556 + 300 + k] = char_enc[t * 256 + k];
}

// ---------------- K4: word BiLSTM, persistent, 64 fat blocks, barrier-free --------
// 64 blocks = 2 dirs x 32 slices; 8 waves (512 thr); block owns 16 h-elems; wave w
// owns elems E0+2w, E0+2w+1. In-wave: lane=r*8+s; r in [0,8): gate q=r>>1, parity
// e=r&1; s splits K 8 ways. Wave 0 = dual-role poller (batched all-at-once re-poll
// of 512 words, 8/lane stride-64) -> LDS stage -> lgkmcnt -> flag bump -> computes.
// Waves 1-7 spin on the LDS flag. Wave-local cell (butterfly + 4 shuffles), publish
// from lanes 0/32, ip for t+1 computed in the publish->detect shadow. No loop
// barriers (dataflow bounds skew). Halved participants vs R7: 64 blocks, 64 pollers.
__global__ __launch_bounds__(512, 1) void k4_wordlstm(
        const float* __restrict__ wWih_f, const float* __restrict__ wWhh_f,
        const float* __restrict__ wbih_f, const float* __restrict__ wbhh_f,
        const float* __restrict__ wWih_b, const float* __restrict__ wWhh_b,
        const float* __restrict__ wbih_b, const float* __restrict__ wbhh_b,
        float* __restrict__ ws) {
    const int tid = threadIdx.x;
    const int w = tid >> 6;               // wave 0..7
    const int lane = tid & 63;
    const int dir = blockIdx.x >> 5;
    const int slice = blockIdx.x & 31;
    const int E0 = slice * 16;
    const int r = lane >> 3, s = lane & 7;
    const int q = r >> 1, e = r & 1;
    const int elem = E0 + 2 * w + e;
    const int grow = q * 512 + elem;      // this lane's gate row

    const float* Wih = dir ? wWih_b : wWih_f;
    const float* Whh = dir ? wWhh_b : wWhh_f;
    const float* bih = dir ? wbih_b : wbih_f;
    const float* bhh = dir ? wbhh_b : wbhh_f;
    const float* wc = ws + OFF_WC;
    uint32* hT = (uint32*)(ws + OFF_H) + (size_t)dir * HSLOT;
    float* hfin = ws + OFF_HFIN;

    const float bz = bih[grow] + bhh[grow];
    const float bzs = (s == 0) ? bz : 0.0f;   // add bias exactly once per row

    // Whh row chunks -> registers (chunk idx = s+8j, j=0..15)
    float4 wr[16];
#pragma unroll
    for (int j = 0; j < 16; j++)
        wr[j] = *(const float4*)&Whh[grow * 512 + (s + 8 * j) * 4];
    // Wih row chunks -> registers (139 float4 chunks; cc = s+8*cj)
    float4 wih[18];
#pragma unroll
    for (int cj = 0; cj < 18; cj++) {
        int cc = s + 8 * cj;
        if (cc < 139) wih[cj] = *(const float4*)&Wih[grow * 556 + cc * 4];
        else { wih[cj].x = wih[cj].y = wih[cj].z = wih[cj].w = 0.0f; }
    }

    __shared__ __align__(16) uint32 hbuf[2][512];  // staged h double buffer
    __shared__ int flag[2];                        // per-parity arrival flags

    if (tid < 2) flag[tid] = 0;
    __syncthreads();   // one-time init barrier (outside the loop)

    float cstate = 0.0f;
    const int eh = lane >> 5;              // which of the wave's 2 elems this half updates

    // input projection for t=0 (per-lane partial from global wc; L2-hit loads)
    float acc_ih = bzs;
    {
        const float* wcrow = wc + (size_t)(dir ? 2047 : 0) * 556;
#pragma unroll
        for (int cj = 0; cj < 18; cj++) {
            int cc = s + 8 * cj;
            if (cc < 139) {
                float4 b = *(const float4*)&wcrow[cc * 4];
                acc_ih += wih[cj].x * b.x + wih[cj].y * b.y + wih[cj].z * b.z + wih[cj].w * b.w;
            }
        }
    }

    for (int t = 0; t < 2048; t++) {
        const int par = t & 1;
        // --- acquire h_t ---
        if (w == 0) {
            uint32* hs = hT + (size_t)t * 512;
            uint32 v[8];
            while (true) {   // batched re-poll: ALL 8 words re-issued every round
#pragma unroll
                for (int m = 0; m < 8; m++)
                    v[m] = __hip_atomic_load(&hs[lane + 64 * m], __ATOMIC_RELAXED, __HIP_MEMORY_SCOPE_AGENT);
                uint32 bad = 0;
#pragma unroll
                for (int m = 0; m < 8; m++) bad |= (v[m] == SENT) ? 1u : 0u;
                if (!__any(bad)) break;
            }
            uint32* bufp = hbuf[par];
#pragma unroll
            for (int m = 0; m < 8; m++) bufp[lane + 64 * m] = v[m];   // 2 lanes/bank: free
            asm volatile("s_waitcnt lgkmcnt(0)" ::: "memory");
            if (lane == 0) *(volatile int*)&flag[par] = t + 1;
        } else {
            while (*(volatile int*)&flag[par] < t + 1) { }
            asm volatile("" ::: "memory");
        }
        // --- recurrent FMA from LDS (b128 reads, conflict-free) ---
        float acc = acc_ih;
        {
            const float* hb = (const float*)hbuf[par];
#pragma unroll
            for (int j = 0; j < 16; j++) {
                float4 hq = *(const float4*)&hb[(s + 8 * j) * 4];
                acc += wr[j].x * hq.x + wr[j].y * hq.y + wr[j].z * hq.z + wr[j].w * hq.w;
            }
        }
        // --- butterfly reduce over K-split (s bits) ---
        acc += __shfl_xor(acc, 1);
        acc += __shfl_xor(acc, 2);
        acc += __shfl_xor(acc, 4);
        // --- gather 4 gates for this half's elem; wave-parallel cell update ---
        float zi = __shfl(acc, 8 * eh);          // row eh     (gate i)
        float zf = __shfl(acc, 16 + 8 * eh);     // row 2+eh   (gate f)
        float zg = __shfl(acc, 32 + 8 * eh);     // row 4+eh   (gate g)
        float zo = __shfl(acc, 48 + 8 * eh);     // row 6+eh   (gate o)
        float cn = sigmoidf_(zf) * cstate + sigmoidf_(zi) * tanhf_(zg);
        cstate = cn;
        float hv = sigmoidf_(zo) * tanhf_(cn);
        // --- publish h_{t+1} immediately (lanes 0 and 32 of each wave) ---
        if ((lane & 31) == 0) {
            int eidx = E0 + 2 * w + eh;
            __hip_atomic_store(&hT[(size_t)(t + 1) * 512 + eidx], __float_as_uint(hv),
                               __ATOMIC_RELAXED, __HIP_MEMORY_SCOPE_AGENT);
            if (t == 2047) hfin[dir * 512 + eidx] = hv;
        }
        // --- input projection for t+1 (hidden in publish->detect gap) ---
        if (t < 2047) {
            acc_ih = bzs;
            const float* wcrow = wc + (size_t)(dir ? (2046 - t) : (t + 1)) * 556;
#pragma unroll
            for (int cj = 0; cj < 18; cj++) {
                int cc = s + 8 * cj;
                if (cc < 139) {
                    float4 b = *(const float4*)&wcrow[cc * 4];
                    acc_ih += wih[cj].x * b.x + wih[cj].y * b.y + wih[cj].z * b.z + wih[cj].w * b.w;
                }
            }
        }
    }
}

// ---------------- K5: classifier head + softmax ----------------
__global__ __launch_bounds__(256) void k5_head(
        const float* __restrict__ ws,
        const float* __restrict__ fc1_w, const float* __restrict__ fc1_b,
        const float* __restrict__ fc2_w, const float* __restrict__ fc2_b,
        float* __restrict__ out) {
    __shared__ float hl[1024];
    __shared__ float z1[512];
    __shared__ float z2[20];
    const int tid = threadIdx.x;
    const float* hfin = ws + OFF_HFIN;
    for (int i = tid; i < 1024; i += 256) hl[i] = hfin[i];
    __syncthreads();
    for (int o = tid; o < 512; o += 256) {
        float a = fc1_b[o];
        const float* wrow = fc1_w + o * 1024;
        for (int k = 0; k < 1024; k++) a += wrow[k] * hl[k];
        z1[o] = fmaxf(a, 0.0f);
    }
    __syncthreads();
    if (tid < 20) {
        float a = fc2_b[tid];
        const float* wrow = fc2_w + tid * 512;
        for (int k = 0; k < 512; k++) a += wrow[k] * z1[k];
        z2[tid] = a;
    }
    __syncthreads();
    if (tid == 0) {
        float m = -1e30f;
        for (int i = 0; i < 20; i++) m = fmaxf(m, z2[i]);
        float sum = 0.0f, ex[20];
        for (int i = 0; i < 20; i++) { ex[i] = __expf(z2[i] - m); sum += ex[i]; }
        for (int i = 0; i < 20; i++) out[i] = ex[i] / sum;
    }
}

extern "C" void kernel_launch(void* const* d_in, const int* in_sizes, int n_in,
                              void* d_out, int out_size, void* d_ws, size_t ws_size,
                              hipStream_t stream) {
    const int*   sc     = (const int*)d_in[0];
    const int*   sw     = (const int*)d_in[1];
    const float* cemb   = (const float*)d_in[2];
    const float* cWih_f = (const float*)d_in[3];
    const float* cWhh_f = (const float*)d_in[4];
    const float* cbih_f = (const float*)d_in[5];
    const float* cbhh_f = (const float*)d_in[6];
    const float* cWih_b = (const float*)d_in[7];
    const float* cWhh_b = (const float*)d_in[8];
    const float* cbih_b = (const float*)d_in[9];
    const float* cbhh_b = (const float*)d_in[10];
    const float* wemb   = (const float*)d_in[11];
    const float* wWih_f = (const float*)d_in[12];
    const float* wWhh_f = (const float*)d_in[13];
    const float* wbih_f = (const float*)d_in[14];
    const float* wbhh_f = (const float*)d_in[15];
    const float* wWih_b = (const float*)d_in[16];
    const float* wWhh_b = (const float*)d_in[17];
    const float* wbih_b = (const float*)d_in[18];
    const float* wbhh_b = (const float*)d_in[19];
    const float* fc1_w  = (const float*)d_in[20];
    const float* fc1_b  = (const float*)d_in[21];
    const float* fc2_w  = (const float*)d_in[22];
    const float* fc2_b  = (const float*)d_in[23];
    float* ws = (float*)d_ws;
    float* out = (float*)d_out;

    k0_prep<<<256, 256, 0, stream>>>(cWih_f, cWhh_f, cWih_b, cWhh_b, ws);
    k1_charlstm<<<512, 256, 0, stream>>>(sc, cemb, ws, cbih_f, cbhh_f, cbih_b, cbhh_b);
    k2_wc<<<2048, 256, 0, stream>>>(sw, wemb, ws);
    k4_wordlstm<<<64, 512, 0, stream>>>(wWih_f, wWhh_f, wbih_f, wbhh_f,
                                        wWih_b, wWhh_b, wbih_b, wbhh_b, ws);
    k5_head<<<1, 256, 0, stream>>>(ws, fc1_w, fc1_b, fc2_w, fc2_b, out);
}

// Round 11
// 4095.395 us; speedup vs baseline: 1.5046x; 1.3485x over previous
//
#include <hip/hip_runtime.h>
#include <math.h>

// dims
#define SDIM 2048
#define LDIM 16
#define ECD 64
#define HCD 128
#define EWD 300
#define HWD 512
#define DWD 556
#define FCD 512
#define OUTD 20

typedef unsigned int uint32;

// ws layout (float offsets)
static constexpr int OFF_CWIHT = 0;         // [2][64][512]   = 65536
static constexpr int OFF_CWHHT = 65536;     // [2][128][512]  = 131072
static constexpr int OFF_CENC  = 196608;    // [2048][256]    = 524288
static constexpr int OFF_WC    = 720896;    // [2048][556]    = 1138688
static constexpr int OFF_H     = 1859584;   // [2][2049][512] = 2098176 (uint32 bit patterns)
static constexpr int OFF_HFIN  = 3957760;   // [1024]
// total ~15.8 MB of ws

#define SENT 0xFFFFFFFFu   // -NaN bit pattern; h = sigmoid*tanh in (-1,1) never produces it
#define HSLOT 1049088      // 2049*512

__device__ __forceinline__ float sigmoidf_(float x) {
    return 1.0f / (1.0f + __expf(-x));
}
__device__ __forceinline__ float tanhf_(float x) {
    x = fminf(10.0f, fmaxf(-10.0f, x));
    float e2 = __expf(2.0f * x);
    return (e2 - 1.0f) / (e2 + 1.0f);
}

// ---------------- K0: transpose char weights + sentinel-fill h slots ----------------
__global__ void k0_prep(const float* __restrict__ cWih_f, const float* __restrict__ cWhh_f,
                        const float* __restrict__ cWih_b, const float* __restrict__ cWhh_b,
                        float* __restrict__ ws) {
    const int nt = gridDim.x * blockDim.x;
    const int t0 = blockIdx.x * blockDim.x + threadIdx.x;
    float* cWihT = ws + OFF_CWIHT;
    float* cWhhT = ws + OFF_CWHHT;
    uint32* hT = (uint32*)(ws + OFF_H);
    for (int i = t0; i < 2 * 512 * 64; i += nt) {
        int d = i / (512 * 64), rem = i % (512 * 64);
        int r = rem / 64, k = rem % 64;
        const float* src = d ? cWih_b : cWih_f;
        cWihT[(d * 64 + k) * 512 + r] = src[r * 64 + k];
    }
    for (int i = t0; i < 2 * 512 * 128; i += nt) {
        int d = i / (512 * 128), rem = i % (512 * 128);
        int r = rem / 128, k = rem % 128;
        const float* src = d ? cWhh_b : cWhh_f;
        cWhhT[(d * 128 + k) * 512 + r] = src[r * 128 + k];
    }
    // h slots: slot 0 = zeros (h_{-1}), slots 1..2048 = sentinel
    for (int i = t0; i < 2 * HSLOT; i += nt) {
        int rel = i % HSLOT;
        hT[i] = (rel < 512) ? 0u : SENT;
    }
}

// ---------------- K1: char BiLSTM (batch 2048, T=16) ----------------
__global__ __launch_bounds__(256) void k1_charlstm(
        const int* __restrict__ sc, const float* __restrict__ cemb,
        float* __restrict__ ws,
        const float* __restrict__ cbih_f, const float* __restrict__ cbhh_f,
        const float* __restrict__ cbih_b, const float* __restrict__ cbhh_b) {
    const int tid = threadIdx.x;
    const int dir = blockIdx.x >> 8;
    const int w0 = (blockIdx.x & 255) * 8;
    const float* WihT = ws + OFF_CWIHT + dir * 64 * 512;   // [64][512]
    const float* WhhT = ws + OFF_CWHHT + dir * 128 * 512;  // [128][512]
    float* char_enc = ws + OFF_CENC;
    const float* bih = dir ? cbih_b : cbih_f;
    const float* bhh = dir ? cbhh_b : cbhh_f;

    __shared__ __align__(16) float x_lds[8][64];
    __shared__ __align__(16) float h_lds[8][128];
    __shared__ float fo_lds[2][8][128];

    const int r0 = tid, r1 = tid + 256;
    const float bz0 = bih[r0] + bhh[r0];
    const float bz1 = bih[r1] + bhh[r1];

    for (int i = tid; i < 8 * 128; i += 256) ((float*)h_lds)[i] = 0.0f;
    float c[8];
#pragma unroll
    for (int w = 0; w < 8; w++) c[w] = 0.0f;
    __syncthreads();

    for (int t = 0; t < 16; t++) {
        const int tx = dir ? (15 - t) : t;
        {   // gather x: 8 words x 64 dims
            int w = tid >> 6, e = tid & 63;
            int i0 = sc[(w0 + w) * 16 + tx];
            x_lds[w][e] = cemb[i0 * 64 + e];
            int i1 = sc[(w0 + w + 4) * 16 + tx];
            x_lds[w + 4][e] = cemb[i1 * 64 + e];
        }
        __syncthreads();

        float a0[8], a1[8];
#pragma unroll
        for (int w = 0; w < 8; w++) { a0[w] = bz0; a1[w] = bz1; }

        // Wih part (K=64)
        for (int k = 0; k < 64; k += 4) {
            float w00 = WihT[(k + 0) * 512 + r0], w01 = WihT[(k + 1) * 512 + r0];
            float w02 = WihT[(k + 2) * 512 + r0], w03 = WihT[(k + 3) * 512 + r0];
            float w10 = WihT[(k + 0) * 512 + r1], w11 = WihT[(k + 1) * 512 + r1];
            float w12 = WihT[(k + 2) * 512 + r1], w13 = WihT[(k + 3) * 512 + r1];
#pragma unroll
            for (int w = 0; w < 8; w++) {
                float4 xq = *(const float4*)&x_lds[w][k];
                a0[w] += w00 * xq.x + w01 * xq.y + w02 * xq.z + w03 * xq.w;
                a1[w] += w10 * xq.x + w11 * xq.y + w12 * xq.z + w13 * xq.w;
            }
        }
        // Whh part (K=128)
        for (int k = 0; k < 128; k += 4) {
            float w00 = WhhT[(k + 0) * 512 + r0], w01 = WhhT[(k + 1) * 512 + r0];
            float w02 = WhhT[(k + 2) * 512 + r0], w03 = WhhT[(k + 3) * 512 + r0];
            float w10 = WhhT[(k + 0) * 512 + r1], w11 = WhhT[(k + 1) * 512 + r1];
            float w12 = WhhT[(k + 2) * 512 + r1], w13 = WhhT[(k + 3) * 512 + r1];
#pragma unroll
            for (int w = 0; w < 8; w++) {
                float4 hq = *(const float4*)&h_lds[w][k];
                a0[w] += w00 * hq.x + w01 * hq.y + w02 * hq.z + w03 * hq.w;
                a1[w] += w10 * hq.x + w11 * hq.y + w12 * hq.z + w13 * hq.w;
            }
        }
        if (tid >= 128) {
            int e = tid - 128;
#pragma unroll
            for (int w = 0; w < 8; w++) { fo_lds[0][w][e] = a0[w]; fo_lds[1][w][e] = a1[w]; }
        }
        __syncthreads();
        if (tid < 128) {
            int e = tid;
#pragma unroll
            for (int w = 0; w < 8; w++) {
                float zi = a0[w], zg = a1[w];
                float zf = fo_lds[0][w][e], zo = fo_lds[1][w][e];
                float cn = sigmoidf_(zf) * c[w] + sigmoidf_(zi) * tanhf_(zg);
                c[w] = cn;
                h_lds[w][e] = sigmoidf_(zo) * tanhf_(cn);
            }
        }
        __syncthreads();
    }
    if (tid < 128) {
        int e = tid;
        for (int w = 0; w < 8; w++)
            char_enc[(w0 + w) * 256 + dir * 128 + e] = h_lds[w][e];
    }
}

// ---------------- K2: build wc = [word_emb | char_enc] ----------------
__global__ void k2_wc(const int* __restrict__ sw, const float* __restrict__ wemb,
                      float* __restrict__ ws) {
    const int t = blockIdx.x;
    const int tid = threadIdx.x;
    const float* char_enc = ws + OFF_CENC;
    float* wc = ws + OFF_WC;
    const int widx = sw[t];
    for (int k = tid; k < 300; k += 256) wc[t * 556 + k] = wemb[widx * 300 + k];
    for (int k = tid; k < 256; k += 256) wc[t * 556 + 300 + k] = char_enc[t * 256 + k];
}

// ---------------- K4: word BiLSTM, persistent, value-signaled ----------------
// 128 blocks = 2 dirs x 64 slices; slice owns h-elems [slice*8, slice*8+8).
// r = tid>>3 in [0,32): gate q=r>>3, elem e=r&7; s = tid&7 splits K=512 into 8x64.
// h published per timestep slot via relaxed agent atomics; consumers poll the
// values themselves (sentinel 0xFFFFFFFF): batched re-poll, issue hidden under
// the input-projection compute. No fences, no flags.
__global__ __launch_bounds__(256, 1) void k4_wordlstm(
        const float* __restrict__ wWih_f, const float* __restrict__ wWhh_f,
        const float* __restrict__ wbih_f, const float* __restrict__ wbhh_f,
        const float* __restrict__ wWih_b, const float* __restrict__ wWhh_b,
        const float* __restrict__ wbih_b, const float* __restrict__ wbhh_b,
        float* __restrict__ ws) {
    const int tid = threadIdx.x;
    const int dir = blockIdx.x >> 6;
    const int slice = blockIdx.x & 63;
    const int E0 = slice * 8;
    const int r = tid >> 3, s = tid & 7;
    const int q = r >> 3, e = r & 7;
    const int grow = q * 512 + E0 + e;

    const float* Wih = dir ? wWih_b : wWih_f;
    const float* Whh = dir ? wWhh_b : wWhh_f;
    const float* bih = dir ? wbih_b : wbih_f;
    const float* bhh = dir ? wbhh_b : wbhh_f;
    const float* wc = ws + OFF_WC;
    uint32* hT = (uint32*)(ws + OFF_H) + (size_t)dir * HSLOT;
    float* hfin = ws + OFF_HFIN;

    const float bz = bih[grow] + bhh[grow];

    // Whh row chunks -> registers (chunk idx = s+8j, j=0..15)
    float4 wr[16];
#pragma unroll
    for (int j = 0; j < 16; j++)
        wr[j] = *(const float4*)&Whh[grow * 512 + (s + 8 * j) * 4];
    // Wih row chunks -> registers (139 float4 chunks; cc = s+8*cj)
    float4 wih[18];
#pragma unroll
    for (int cj = 0; cj < 18; cj++) {
        int cc = s + 8 * cj;
        if (cc < 139) wih[cj] = *(const float4*)&Wih[grow * 556 + cc * 4];
        else { wih[cj].x = wih[cj].y = wih[cj].z = wih[cj].w = 0.0f; }
    }

    __shared__ __align__(16) float4 wcb[2][140];   // wc row double buffer
    __shared__ __align__(16) float h_lds[512];
    __shared__ float zbuf[32];

    // preload wc row for t=0
    {
        int tx0 = dir ? 2047 : 0;
        if (tid < 139) wcb[0][tid] = *(const float4*)&wc[tx0 * 556 + tid * 4];
    }
    __syncthreads();

    float cstate = 0.0f;
    const int b0 = tid * 4;          // poll/stage words b0..b0+3 (first half)
    const int b1 = 256 + tid * 4;    // and b1..b1+3 (second half)

    for (int t = 0; t < 2048; t++) {
        uint32* hs = hT + (size_t)t * 512;
        // 1) speculative poll batch: issue loads now, consume after ip compute
        uint32 v[8];
        if (tid < 64) {
#pragma unroll
            for (int m = 0; m < 4; m++)
                v[m] = __hip_atomic_load(&hs[b0 + m], __ATOMIC_RELAXED, __HIP_MEMORY_SCOPE_AGENT);
#pragma unroll
            for (int m = 0; m < 4; m++)
                v[4 + m] = __hip_atomic_load(&hs[b1 + m], __ATOMIC_RELAXED, __HIP_MEMORY_SCOPE_AGENT);
        }
        // 2) issue next wc row prefetch (off critical path)
        float4 pf;
        const bool havepf = (t < 2047) && (tid < 139);
        if (havepf) {
            int txn = dir ? (2046 - t) : (t + 1);
            pf = *(const float4*)&wc[txn * 556 + tid * 4];
        }
        // 3) input projection from LDS wc buffer (overlaps the in-flight poll)
        float acc = 0.0f;
        {
            const float4* wrow = wcb[t & 1];
#pragma unroll
            for (int cj = 0; cj < 18; cj++) {
                int cc = s + 8 * cj;
                if (cc < 139) {
                    float4 b = wrow[cc];
                    acc += wih[cj].x * b.x + wih[cj].y * b.y + wih[cj].z * b.z + wih[cj].w * b.w;
                }
            }
        }
        // 4) check + batched re-poll until all 8 words are non-sentinel
        if (tid < 64) {
            while (true) {
                uint32 bad = 0;
#pragma unroll
                for (int m = 0; m < 8; m++) bad |= (v[m] == SENT) ? 1u : 0u;
                if (!bad) break;
#pragma unroll
                for (int m = 0; m < 4; m++)
                    v[m] = __hip_atomic_load(&hs[b0 + m], __ATOMIC_RELAXED, __HIP_MEMORY_SCOPE_AGENT);
#pragma unroll
                for (int m = 0; m < 4; m++)
                    v[4 + m] = __hip_atomic_load(&hs[b1 + m], __ATOMIC_RELAXED, __HIP_MEMORY_SCOPE_AGENT);
            }
            // stage as two b128 writes (lane-stride 16B: conflict-free)
            *(uint4*)&((uint32*)h_lds)[b0] = uint4{v[0], v[1], v[2], v[3]};
            *(uint4*)&((uint32*)h_lds)[b1] = uint4{v[4], v[5], v[6], v[7]};
        }
        __syncthreads();
        // 5) recurrent FMA from LDS
#pragma unroll
        for (int j = 0; j < 16; j++) {
            float4 hq = *(const float4*)&h_lds[(s + 8 * j) * 4];
            acc += wr[j].x * hq.x + wr[j].y * hq.y + wr[j].z * hq.z + wr[j].w * hq.w;
        }
        // 6) reduce 8 K-partials (lanes differing in low-3 bits)
        acc += __shfl_xor(acc, 1);
        acc += __shfl_xor(acc, 2);
        acc += __shfl_xor(acc, 4);
        if (s == 0) zbuf[r] = acc + bz;
        __syncthreads();
        // 7) cell update + publish h_{t+1}
        if (tid < 8) {
            float zi = zbuf[tid], zf = zbuf[8 + tid], zg = zbuf[16 + tid], zo = zbuf[24 + tid];
            float cn = sigmoidf_(zf) * cstate + sigmoidf_(zi) * tanhf_(zg);
            cstate = cn;
            float hv = sigmoidf_(zo) * tanhf_(cn);
            uint32* hd = hT + (size_t)(t + 1) * 512;
            __hip_atomic_store(&hd[E0 + tid], __float_as_uint(hv),
                               __ATOMIC_RELAXED, __HIP_MEMORY_SCOPE_AGENT);
            if (t == 2047) hfin[dir * 512 + E0 + tid] = hv;
        }
        // 8) land wc prefetch into LDS for next step
        if (havepf) wcb[(t + 1) & 1][tid] = pf;
        __syncthreads();
    }
}

// ---------------- K5: classifier head + softmax ----------------
__global__ __launch_bounds__(256) void k5_head(
        const float* __restrict__ ws,
        const float* __restrict__ fc1_w, const float* __restrict__ fc1_b,
        const float* __restrict__ fc2_w, const float* __restrict__ fc2_b,
        float* __restrict__ out) {
    __shared__ float hl[1024];
    __shared__ float z1[512];
    __shared__ float z2[20];
    const int tid = threadIdx.x;
    const float* hfin = ws + OFF_HFIN;
    for (int i = tid; i < 1024; i += 256) hl[i] = hfin[i];
    __syncthreads();
    for (int o = tid; o < 512; o += 256) {
        float a = fc1_b[o];
        const float* wrow = fc1_w + o * 1024;
        for (int k = 0; k < 1024; k++) a += wrow[k] * hl[k];
        z1[o] = fmaxf(a, 0.0f);
    }
    __syncthreads();
    if (tid < 20) {
        float a = fc2_b[tid];
        const float* wrow = fc2_w + tid * 512;
        for (int k = 0; k < 512; k++) a += wrow[k] * z1[k];
        z2[tid] = a;
    }
    __syncthreads();
    if (tid == 0) {
        float m = -1e30f;
        for (int i = 0; i < 20; i++) m = fmaxf(m, z2[i]);
        float sum = 0.0f, ex[20];
        for (int i = 0; i < 20; i++) { ex[i] = __expf(z2[i] - m); sum += ex[i]; }
        for (int i = 0; i < 20; i++) out[i] = ex[i] / sum;
    }
}

extern "C" void kernel_launch(void* const* d_in, const int* in_sizes, int n_in,
                              void* d_out, int out_size, void* d_ws, size_t ws_size,
                              hipStream_t stream) {
    const int*   sc     = (const int*)d_in[0];
    const int*   sw     = (const int*)d_in[1];
    const float* cemb   = (const float*)d_in[2];
    const float* cWih_f = (const float*)d_in[3];
    const float* cWhh_f = (const float*)d_in[4];
    const float* cbih_f = (const float*)d_in[5];
    const float* cbhh_f = (const float*)d_in[6];
    const float* cWih_b = (const float*)d_in[7];
    const float* cWhh_b = (const float*)d_in[8];
    const float* cbih_b = (const float*)d_in[9];
    const float* cbhh_b = (const float*)d_in[10];
    const float* wemb   = (const float*)d_in[11];
    const float* wWih_f = (const float*)d_in[12];
    const float* wWhh_f = (const float*)d_in[13];
    const float* wbih_f = (const float*)d_in[14];
    const float* wbhh_f = (const float*)d_in[15];
    const float* wWih_b = (const float*)d_in[16];
    const float* wWhh_b = (const float*)d_in[17];
    const float* wbih_b = (const float*)d_in[18];
    const float* wbhh_b = (const float*)d_in[19];
    const float* fc1_w  = (const float*)d_in[20];
    const float* fc1_b  = (const float*)d_in[21];
    const float* fc2_w  = (const float*)d_in[22];
    const float* fc2_b  = (const float*)d_in[23];
    float* ws = (float*)d_ws;
    float* out = (float*)d_out;

    k0_prep<<<256, 256, 0, stream>>>(cWih_f, cWhh_f, cWih_b, cWhh_b, ws);
    k1_charlstm<<<512, 256, 0, stream>>>(sc, cemb, ws, cbih_f, cbhh_f, cbih_b, cbhh_b);
    k2_wc<<<2048, 256, 0, stream>>>(sw, wemb, ws);
    k4_wordlstm<<<128, 256, 0, stream>>>(wWih_f, wWhh_f, wbih_f, wbhh_f,
                                         wWih_b, wWhh_b, wbih_b, wbhh_b, ws);
    k5_head<<<1, 256, 0, stream>>>(ws, fc1_w, fc1_b, fc2_w, fc2_b, out);
}

// Round 12
// 4078.670 us; speedup vs baseline: 1.5108x; 1.0041x over previous
//
#include <hip/hip_runtime.h>
#include <math.h>

// dims
#define SDIM 2048
#define LDIM 16
#define ECD 64
#define HCD 128
#define EWD 300
#define HWD 512
#define DWD 556
#define FCD 512
#define OUTD 20

typedef unsigned int uint32;

// ws layout (float offsets)
static constexpr int OFF_CWIHT = 0;         // [2][64][512]   = 65536
static constexpr int OFF_CWHHT = 65536;     // [2][128][512]  = 131072
static constexpr int OFF_CENC  = 196608;    // [2048][256]    = 524288
static constexpr int OFF_WC    = 720896;    // [2048][556]    = 1138688
static constexpr int OFF_H     = 1859584;   // [2][2049][512] = 2098176 (uint32 bit patterns)
static constexpr int OFF_HFIN  = 3957760;   // [1024]
// total ~15.8 MB of ws

#define SENT 0xFFFFFFFFu   // -NaN bit pattern; h = sigmoid*tanh in (-1,1) never produces it
#define HSLOT 1049088      // 2049*512

__device__ __forceinline__ float sigmoidf_(float x) {
    return 1.0f / (1.0f + __expf(-x));
}
__device__ __forceinline__ float tanhf_(float x) {
    x = fminf(10.0f, fmaxf(-10.0f, x));
    float e2 = __expf(2.0f * x);
    return (e2 - 1.0f) / (e2 + 1.0f);
}

// ---------------- K0: transpose char weights + sentinel-fill h slots ----------------
__global__ void k0_prep(const float* __restrict__ cWih_f, const float* __restrict__ cWhh_f,
                        const float* __restrict__ cWih_b, const float* __restrict__ cWhh_b,
                        float* __restrict__ ws) {
    const int nt = gridDim.x * blockDim.x;
    const int t0 = blockIdx.x * blockDim.x + threadIdx.x;
    float* cWihT = ws + OFF_CWIHT;
    float* cWhhT = ws + OFF_CWHHT;
    uint32* hT = (uint32*)(ws + OFF_H);
    for (int i = t0; i < 2 * 512 * 64; i += nt) {
        int d = i / (512 * 64), rem = i % (512 * 64);
        int r = rem / 64, k = rem % 64;
        const float* src = d ? cWih_b : cWih_f;
        cWihT[(d * 64 + k) * 512 + r] = src[r * 64 + k];
    }
    for (int i = t0; i < 2 * 512 * 128; i += nt) {
        int d = i / (512 * 128), rem = i % (512 * 128);
        int r = rem / 128, k = rem % 128;
        const float* src = d ? cWhh_b : cWhh_f;
        cWhhT[(d * 128 + k) * 512 + r] = src[r * 128 + k];
    }
    // h slots: slot 0 = zeros (h_{-1}), slots 1..2048 = sentinel
    for (int i = t0; i < 2 * HSLOT; i += nt) {
        int rel = i % HSLOT;
        hT[i] = (rel < 512) ? 0u : SENT;
    }
}

// ---------------- K1: char BiLSTM (batch 2048, T=16) ----------------
__global__ __launch_bounds__(256) void k1_charlstm(
        const int* __restrict__ sc, const float* __restrict__ cemb,
        float* __restrict__ ws,
        const float* __restrict__ cbih_f, const float* __restrict__ cbhh_f,
        const float* __restrict__ cbih_b, const float* __restrict__ cbhh_b) {
    const int tid = threadIdx.x;
    const int dir = blockIdx.x >> 8;
    const int w0 = (blockIdx.x & 255) * 8;
    const float* WihT = ws + OFF_CWIHT + dir * 64 * 512;   // [64][512]
    const float* WhhT = ws + OFF_CWHHT + dir * 128 * 512;  // [128][512]
    float* char_enc = ws + OFF_CENC;
    const float* bih = dir ? cbih_b : cbih_f;
    const float* bhh = dir ? cbhh_b : cbhh_f;

    __shared__ __align__(16) float x_lds[8][64];
    __shared__ __align__(16) float h_lds[8][128];
    __shared__ float fo_lds[2][8][128];

    const int r0 = tid, r1 = tid + 256;
    const float bz0 = bih[r0] + bhh[r0];
    const float bz1 = bih[r1] + bhh[r1];

    for (int i = tid; i < 8 * 128; i += 256) ((float*)h_lds)[i] = 0.0f;
    float c[8];
#pragma unroll
    for (int w = 0; w < 8; w++) c[w] = 0.0f;
    __syncthreads();

    for (int t = 0; t < 16; t++) {
        const int tx = dir ? (15 - t) : t;
        {   // gather x: 8 words x 64 dims
            int w = tid >> 6, e = tid & 63;
            int i0 = sc[(w0 + w) * 16 + tx];
            x_lds[w][e] = cemb[i0 * 64 + e];
            int i1 = sc[(w0 + w + 4) * 16 + tx];
            x_lds[w + 4][e] = cemb[i1 * 64 + e];
        }
        __syncthreads();

        float a0[8], a1[8];
#pragma unroll
        for (int w = 0; w < 8; w++) { a0[w] = bz0; a1[w] = bz1; }

        // Wih part (K=64)
        for (int k = 0; k < 64; k += 4) {
            float w00 = WihT[(k + 0) * 512 + r0], w01 = WihT[(k + 1) * 512 + r0];
            float w02 = WihT[(k + 2) * 512 + r0], w03 = WihT[(k + 3) * 512 + r0];
            float w10 = WihT[(k + 0) * 512 + r1], w11 = WihT[(k + 1) * 512 + r1];
            float w12 = WihT[(k + 2) * 512 + r1], w13 = WihT[(k + 3) * 512 + r1];
#pragma unroll
            for (int w = 0; w < 8; w++) {
                float4 xq = *(const float4*)&x_lds[w][k];
                a0[w] += w00 * xq.x + w01 * xq.y + w02 * xq.z + w03 * xq.w;
                a1[w] += w10 * xq.x + w11 * xq.y + w12 * xq.z + w13 * xq.w;
            }
        }
        // Whh part (K=128)
        for (int k = 0; k < 128; k += 4) {
            float w00 = WhhT[(k + 0) * 512 + r0], w01 = WhhT[(k + 1) * 512 + r0];
            float w02 = WhhT[(k + 2) * 512 + r0], w03 = WhhT[(k + 3) * 512 + r0];
            float w10 = WhhT[(k + 0) * 512 + r1], w11 = WhhT[(k + 1) * 512 + r1];
            float w12 = WhhT[(k + 2) * 512 + r1], w13 = WhhT[(k + 3) * 512 + r1];
#pragma unroll
            for (int w = 0; w < 8; w++) {
                float4 hq = *(const float4*)&h_lds[w][k];
                a0[w] += w00 * hq.x + w01 * hq.y + w02 * hq.z + w03 * hq.w;
                a1[w] += w10 * hq.x + w11 * hq.y + w12 * hq.z + w13 * hq.w;
            }
        }
        if (tid >= 128) {
            int e = tid - 128;
#pragma unroll
            for (int w = 0; w < 8; w++) { fo_lds[0][w][e] = a0[w]; fo_lds[1][w][e] = a1[w]; }
        }
        __syncthreads();
        if (tid < 128) {
            int e = tid;
#pragma unroll
            for (int w = 0; w < 8; w++) {
                float zi = a0[w], zg = a1[w];
                float zf = fo_lds[0][w][e], zo = fo_lds[1][w][e];
                float cn = sigmoidf_(zf) * c[w] + sigmoidf_(zi) * tanhf_(zg);
                c[w] = cn;
                h_lds[w][e] = sigmoidf_(zo) * tanhf_(cn);
            }
        }
        __syncthreads();
    }
    if (tid < 128) {
        int e = tid;
        for (int w = 0; w < 8; w++)
            char_enc[(w0 + w) * 256 + dir * 128 + e] = h_lds[w][e];
    }
}

// ---------------- K2: build wc = [word_emb | char_enc] ----------------
__global__ void k2_wc(const int* __restrict__ sw, const float* __restrict__ wemb,
                      float* __restrict__ ws) {
    const int t = blockIdx.x;
    const int tid = threadIdx.x;
    const float* char_enc = ws + OFF_CENC;
    float* wc = ws + OFF_WC;
    const int widx = sw[t];
    for (int k = tid; k < 300; k += 256) wc[t * 556 + k] = wemb[widx * 300 + k];
    for (int k = tid; k < 256; k += 256) wc[t * 556 + 300 + k] = char_enc[t * 256 + k];
}

// ---------------- K4: word BiLSTM, persistent, value-signaled ----------------
// 128 blocks = 2 dirs x 64 slices; slice owns h-elems [slice*8, slice*8+8).
// r = tid>>3 in [0,32): gate q=r>>3, elem e=r&7; s = tid&7 splits K=512 into 8x64.
// h published per timestep slot via relaxed agent atomics; consumers poll the
// values themselves (sentinel 0xFFFFFFFF): batched re-poll with MASKED re-issue
// (only still-sentinel words reloaded per round -> lower MALL request pressure),
// first batch issued speculatively under the input-projection compute.
// No fences, no flags.
__global__ __launch_bounds__(256, 1) void k4_wordlstm(
        const float* __restrict__ wWih_f, const float* __restrict__ wWhh_f,
        const float* __restrict__ wbih_f, const float* __restrict__ wbhh_f,
        const float* __restrict__ wWih_b, const float* __restrict__ wWhh_b,
        const float* __restrict__ wbih_b, const float* __restrict__ wbhh_b,
        float* __restrict__ ws) {
    const int tid = threadIdx.x;
    const int dir = blockIdx.x >> 6;
    const int slice = blockIdx.x & 63;
    const int E0 = slice * 8;
    const int r = tid >> 3, s = tid & 7;
    const int q = r >> 3, e = r & 7;
    const int grow = q * 512 + E0 + e;

    const float* Wih = dir ? wWih_b : wWih_f;
    const float* Whh = dir ? wWhh_b : wWhh_f;
    const float* bih = dir ? wbih_b : wbih_f;
    const float* bhh = dir ? wbhh_b : wbhh_f;
    const float* wc = ws + OFF_WC;
    uint32* hT = (uint32*)(ws + OFF_H) + (size_t)dir * HSLOT;
    float* hfin = ws + OFF_HFIN;

    const float bz = bih[grow] + bhh[grow];

    // Whh row chunks -> registers (chunk idx = s+8j, j=0..15)
    float4 wr[16];
#pragma unroll
    for (int j = 0; j < 16; j++)
        wr[j] = *(const float4*)&Whh[grow * 512 + (s + 8 * j) * 4];
    // Wih row chunks -> registers (139 float4 chunks; cc = s+8*cj)
    float4 wih[18];
#pragma unroll
    for (int cj = 0; cj < 18; cj++) {
        int cc = s + 8 * cj;
        if (cc < 139) wih[cj] = *(const float4*)&Wih[grow * 556 + cc * 4];
        else { wih[cj].x = wih[cj].y = wih[cj].z = wih[cj].w = 0.0f; }
    }

    __shared__ __align__(16) float4 wcb[2][140];   // wc row double buffer
    __shared__ __align__(16) float h_lds[512];
    __shared__ float zbuf[32];

    // preload wc row for t=0
    {
        int tx0 = dir ? 2047 : 0;
        if (tid < 139) wcb[0][tid] = *(const float4*)&wc[tx0 * 556 + tid * 4];
    }
    __syncthreads();

    float cstate = 0.0f;
    const int b0 = tid * 4;          // poll/stage words b0..b0+3 (first half)
    const int b1 = 256 + tid * 4;    // and b1..b1+3 (second half)

    for (int t = 0; t < 2048; t++) {
        uint32* hs = hT + (size_t)t * 512;
        // 1) speculative poll batch: issue loads now, consume after ip compute
        uint32 v[8];
        if (tid < 64) {
#pragma unroll
            for (int m = 0; m < 4; m++)
                v[m] = __hip_atomic_load(&hs[b0 + m], __ATOMIC_RELAXED, __HIP_MEMORY_SCOPE_AGENT);
#pragma unroll
            for (int m = 0; m < 4; m++)
                v[4 + m] = __hip_atomic_load(&hs[b1 + m], __ATOMIC_RELAXED, __HIP_MEMORY_SCOPE_AGENT);
        }
        // 2) issue next wc row prefetch (off critical path)
        float4 pf;
        const bool havepf = (t < 2047) && (tid < 139);
        if (havepf) {
            int txn = dir ? (2046 - t) : (t + 1);
            pf = *(const float4*)&wc[txn * 556 + tid * 4];
        }
        // 3) input projection from LDS wc buffer (overlaps the in-flight poll)
        float acc = 0.0f;
        {
            const float4* wrow = wcb[t & 1];
#pragma unroll
            for (int cj = 0; cj < 18; cj++) {
                int cc = s + 8 * cj;
                if (cc < 139) {
                    float4 b = wrow[cc];
                    acc += wih[cj].x * b.x + wih[cj].y * b.y + wih[cj].z * b.z + wih[cj].w * b.w;
                }
            }
        }
        // 4) check + batched MASKED re-poll until all 8 words are non-sentinel
        //    (only still-sentinel words re-issued each round -> less MALL pressure;
        //     still one batch per round, never per-word dependent waits)
        if (tid < 64) {
            while (true) {
                uint32 bad = 0;
#pragma unroll
                for (int m = 0; m < 8; m++) bad |= (v[m] == SENT) ? 1u : 0u;
                if (!bad) break;
#pragma unroll
                for (int m = 0; m < 4; m++)
                    if (v[m] == SENT)
                        v[m] = __hip_atomic_load(&hs[b0 + m], __ATOMIC_RELAXED, __HIP_MEMORY_SCOPE_AGENT);
#pragma unroll
                for (int m = 0; m < 4; m++)
                    if (v[4 + m] == SENT)
                        v[4 + m] = __hip_atomic_load(&hs[b1 + m], __ATOMIC_RELAXED, __HIP_MEMORY_SCOPE_AGENT);
            }
            // stage as two b128 writes (lane-stride 16B: conflict-free)
            *(uint4*)&((uint32*)h_lds)[b0] = uint4{v[0], v[1], v[2], v[3]};
            *(uint4*)&((uint32*)h_lds)[b1] = uint4{v[4], v[5], v[6], v[7]};
        }
        __syncthreads();
        // 5) recurrent FMA from LDS
#pragma unroll
        for (int j = 0; j < 16; j++) {
            float4 hq = *(const float4*)&h_lds[(s + 8 * j) * 4];
            acc += wr[j].x * hq.x + wr[j].y * hq.y + wr[j].z * hq.z + wr[j].w * hq.w;
        }
        // 6) reduce 8 K-partials (lanes differing in low-3 bits)
        acc += __shfl_xor(acc, 1);
        acc += __shfl_xor(acc, 2);
        acc += __shfl_xor(acc, 4);
        if (s == 0) zbuf[r] = acc + bz;
        __syncthreads();
        // 7) cell update + publish h_{t+1}
        if (tid < 8) {
            float zi = zbuf[tid], zf = zbuf[8 + tid], zg = zbuf[16 + tid], zo = zbuf[24 + tid];
            float cn = sigmoidf_(zf) * cstate + sigmoidf_(zi) * tanhf_(zg);
            cstate = cn;
            float hv = sigmoidf_(zo) * tanhf_(cn);
            uint32* hd = hT + (size_t)(t + 1) * 512;
            __hip_atomic_store(&hd[E0 + tid], __float_as_uint(hv),
                               __ATOMIC_RELAXED, __HIP_MEMORY_SCOPE_AGENT);
            if (t == 2047) hfin[dir * 512 + E0 + tid] = hv;
        }
        // 8) land wc prefetch into LDS for next step
        if (havepf) wcb[(t + 1) & 1][tid] = pf;
        __syncthreads();
    }
}

// ---------------- K5: classifier head + softmax ----------------
__global__ __launch_bounds__(256) void k5_head(
        const float* __restrict__ ws,
        const float* __restrict__ fc1_w, const float* __restrict__ fc1_b,
        const float* __restrict__ fc2_w, const float* __restrict__ fc2_b,
        float* __restrict__ out) {
    __shared__ float hl[1024];
    __shared__ float z1[512];
    __shared__ float z2[20];
    const int tid = threadIdx.x;
    const float* hfin = ws + OFF_HFIN;
    for (int i = tid; i < 1024; i += 256) hl[i] = hfin[i];
    __syncthreads();
    for (int o = tid; o < 512; o += 256) {
        float a = fc1_b[o];
        const float* wrow = fc1_w + o * 1024;
        for (int k = 0; k < 1024; k++) a += wrow[k] * hl[k];
        z1[o] = fmaxf(a, 0.0f);
    }
    __syncthreads();
    if (tid < 20) {
        float a = fc2_b[tid];
        const float* wrow = fc2_w + tid * 512;
        for (int k = 0; k < 512; k++) a += wrow[k] * z1[k];
        z2[tid] = a;
    }
    __syncthreads();
    if (tid == 0) {
        float m = -1e30f;
        for (int i = 0; i < 20; i++) m = fmaxf(m, z2[i]);
        float sum = 0.0f, ex[20];
        for (int i = 0; i < 20; i++) { ex[i] = __expf(z2[i] - m); sum += ex[i]; }
        for (int i = 0; i < 20; i++) out[i] = ex[i] / sum;
    }
}

extern "C" void kernel_launch(void* const* d_in, const int* in_sizes, int n_in,
                              void* d_out, int out_size, void* d_ws, size_t ws_size,
                              hipStream_t stream) {
    const int*   sc     = (const int*)d_in[0];
    const int*   sw     = (const int*)d_in[1];
    const float* cemb   = (const float*)d_in[2];
    const float* cWih_f = (const float*)d_in[3];
    const float* cWhh_f = (const float*)d_in[4];
    const float* cbih_f = (const float*)d_in[5];
    const float* cbhh_f = (const float*)d_in[6];
    const float* cWih_b = (const float*)d_in[7];
    const float* cWhh_b = (const float*)d_in[8];
    const float* cbih_b = (const float*)d_in[9];
    const float* cbhh_b = (const float*)d_in[10];
    const float* wemb   = (const float*)d_in[11];
    const float* wWih_f = (const float*)d_in[12];
    const float* wWhh_f = (const float*)d_in[13];
    const float* wbih_f = (const float*)d_in[14];
    const float* wbhh_f = (const float*)d_in[15];
    const float* wWih_b = (const float*)d_in[16];
    const float* wWhh_b = (const float*)d_in[17];
    const float* wbih_b = (const float*)d_in[18];
    const float* wbhh_b = (const float*)d_in[19];
    const float* fc1_w  = (const float*)d_in[20];
    const float* fc1_b  = (const float*)d_in[21];
    const float* fc2_w  = (const float*)d_in[22];
    const float* fc2_b  = (const float*)d_in[23];
    float* ws = (float*)d_ws;
    float* out = (float*)d_out;

    k0_prep<<<256, 256, 0, stream>>>(cWih_f, cWhh_f, cWih_b, cWhh_b, ws);
    k1_charlstm<<<512, 256, 0, stream>>>(sc, cemb, ws, cbih_f, cbhh_f, cbih_b, cbhh_b);
    k2_wc<<<2048, 256, 0, stream>>>(sw, wemb, ws);
    k4_wordlstm<<<128, 256, 0, stream>>>(wWih_f, wWhh_f, wbih_f, wbhh_f,
                                         wWih_b, wWhh_b, wbih_b, wbhh_b, ws);
    k5_head<<<1, 256, 0, stream>>>(ws, fc1_w, fc1_b, fc2_w, fc2_b, out);
}